// Round 1
// baseline (574.684 us; speedup 1.0000x reference)
//
#include <hip/hip_runtime.h>

#define M_TOK 8192
#define N_OUT 4096
#define K_IN  4096

typedef __bf16 bf16x8 __attribute__((ext_vector_type(8)));
typedef float f32x4 __attribute__((ext_vector_type(4)));

__device__ __forceinline__ unsigned short f2b(float f) {
  union { float f; unsigned u; } c; c.f = f;
  unsigned u = c.u;
  return (unsigned short)((u + 0x7FFFu + ((u >> 16) & 1u)) >> 16);  // RNE
}

// ---------------- kernel 1: x f32 -> bf16 ----------------
__global__ __launch_bounds__(256) void cvt_x_kernel(const float* __restrict__ x,
                                                    unsigned short* __restrict__ xb) {
  long i = ((long)blockIdx.x * 256 + threadIdx.x) * 8;
  float4 a = *(const float4*)(x + i);
  float4 b = *(const float4*)(x + i + 4);
  union { unsigned short us[8]; uint4 v; } o;
  o.us[0] = f2b(a.x); o.us[1] = f2b(a.y); o.us[2] = f2b(a.z); o.us[3] = f2b(a.w);
  o.us[4] = f2b(b.x); o.us[5] = f2b(b.y); o.us[6] = f2b(b.z); o.us[7] = f2b(b.w);
  *(uint4*)(xb + i) = o.v;
}

// ---------------- kernel 2: dequant + blockwise FWHT on W rows ----------------
// W[o, g*1024 + j] = grid[codes[o, g*512 + j/2]][j%2] * scales[o,g]
// W'[o, g*1024 + i] = (1/32) * sum_j H[i,j] W[o, g*1024+j]   (Sylvester H, FWHT)
__global__ __launch_bounds__(256) void dequant_had_kernel(const int* __restrict__ codes,
                                                          const float* __restrict__ grid,
                                                          const float* __restrict__ scales,
                                                          unsigned short* __restrict__ Wt) {
  int o = blockIdx.x >> 2;
  int g = blockIdx.x & 3;
  int t = threadIdx.x;
  __shared__ float buf[1024];
  const int* crow = codes + (long)o * 2048 + g * 512;
  int2 cc = ((const int2*)crow)[t];          // codes for elements 4t..4t+3
  float2 g0 = ((const float2*)grid)[cc.x];
  float2 g1 = ((const float2*)grid)[cc.y];
  buf[4 * t + 0] = g0.x; buf[4 * t + 1] = g0.y;
  buf[4 * t + 2] = g1.x; buf[4 * t + 3] = g1.y;
#pragma unroll
  for (int s = 0; s < 10; s++) {
    __syncthreads();
#pragma unroll
    for (int r = 0; r < 2; r++) {
      int p = t + (r << 8);                              // pair id 0..511
      int i = ((p >> s) << (s + 1)) | (p & ((1 << s) - 1));
      int j = i | (1 << s);
      float a = buf[i], b = buf[j];
      buf[i] = a + b;
      buf[j] = a - b;
    }
  }
  __syncthreads();
  float sc = scales[o * 4 + g] * 0.03125f;               // 1/sqrt(1024)
  unsigned short* wrow = Wt + (long)o * 4096 + g * 1024;
#pragma unroll
  for (int r = 0; r < 4; r++) {
    int e = t + (r << 8);
    wrow[e] = f2b(buf[e] * sc);
  }
}

// ---------------- kernel 3: bf16 GEMM, C = A * B^T + bias ----------------
// A: (M,K) bf16 row-major; B: (N,K) bf16 row-major (i.e. B^T input); C: (M,N) f32
__device__ __forceinline__ void load16_to_lds(const unsigned short* g, unsigned short* l) {
  __builtin_amdgcn_global_load_lds((const __attribute__((address_space(1))) void*)g,
                                   (__attribute__((address_space(3))) void*)l,
                                   16, 0, 0);
}

__global__ __launch_bounds__(256, 2) void gemm_kernel(const unsigned short* __restrict__ A,
                                                      const unsigned short* __restrict__ B,
                                                      const float* __restrict__ bias,
                                                      float* __restrict__ C) {
  __shared__ unsigned short sA[128 * 32];
  __shared__ unsigned short sB[128 * 32];
  const int bm = blockIdx.y * 128;
  const int bn = blockIdx.x * 128;
  const int tid = threadIdx.x;
  const int wave = tid >> 6;
  const int lane = tid & 63;
  const int wm = (wave >> 1) * 64;    // wave's 64x64 subtile
  const int wn = (wave & 1) * 64;

  // staging: each wave fills two 16-row chunks of sA and sB (1 KiB per issue)
  const int srow = lane >> 2;         // 0..15 row within chunk
  const int scol = (lane & 3) * 8;    // k offset in elements
  const long K = K_IN;
  const unsigned short* Ag0 = A + (long)(bm + wave * 16 + srow) * K + scol;
  const unsigned short* Ag1 = A + (long)(bm + (wave + 4) * 16 + srow) * K + scol;
  const unsigned short* Bg0 = B + (long)(bn + wave * 16 + srow) * K + scol;
  const unsigned short* Bg1 = B + (long)(bn + (wave + 4) * 16 + srow) * K + scol;
  unsigned short* lA0 = &sA[(wave * 16) * 32];       // wave-uniform LDS bases
  unsigned short* lA1 = &sA[((wave + 4) * 16) * 32];
  unsigned short* lB0 = &sB[(wave * 16) * 32];
  unsigned short* lB1 = &sB[((wave + 4) * 16) * 32];

  f32x4 acc[4][4] = {};

  const int frow = lane & 15;         // MFMA A/B operand: m (or n) = lane&15
  const int fk = (lane >> 4) * 8;     // k = (lane>>4)*8 + j

  for (int k0 = 0; k0 < K_IN; k0 += 32) {
    __syncthreads();                  // prev iter's LDS reads done
    load16_to_lds(Ag0 + k0, lA0);
    load16_to_lds(Ag1 + k0, lA1);
    load16_to_lds(Bg0 + k0, lB0);
    load16_to_lds(Bg1 + k0, lB1);
    __syncthreads();                  // staging complete
    bf16x8 af[4], bfr[4];
#pragma unroll
    for (int i = 0; i < 4; i++)
      af[i] = *(const bf16x8*)&sA[(wm + i * 16 + frow) * 32 + fk];
#pragma unroll
    for (int i = 0; i < 4; i++)
      bfr[i] = *(const bf16x8*)&sB[(wn + i * 16 + frow) * 32 + fk];
#pragma unroll
    for (int mi = 0; mi < 4; mi++)
#pragma unroll
      for (int ni = 0; ni < 4; ni++)
        acc[mi][ni] = __builtin_amdgcn_mfma_f32_16x16x32_bf16(af[mi], bfr[ni], acc[mi][ni], 0, 0, 0);
  }

  // epilogue: D[m=(lane>>4)*4+r][n=lane&15] per 16x16 tile
  const int cn = lane & 15;
  const int cm = (lane >> 4) * 4;
#pragma unroll
  for (int ni = 0; ni < 4; ni++) {
    const int col = bn + wn + ni * 16 + cn;
    const float bb = bias[col];
#pragma unroll
    for (int mi = 0; mi < 4; mi++) {
#pragma unroll
      for (int r = 0; r < 4; r++) {
        const int row = bm + wm + mi * 16 + cm + r;
        C[(long)row * N_OUT + col] = acc[mi][ni][r] + bb;
      }
    }
  }
}

extern "C" void kernel_launch(void* const* d_in, const int* in_sizes, int n_in,
                              void* d_out, int out_size, void* d_ws, size_t ws_size,
                              hipStream_t stream) {
  const float* x      = (const float*)d_in[0];
  const int*   codes  = (const int*)d_in[1];
  const float* grid   = (const float*)d_in[2];
  const float* scales = (const float*)d_in[3];
  const float* bias   = (const float*)d_in[4];
  float* out = (float*)d_out;

  unsigned short* xb = (unsigned short*)d_ws;                    // 8192*4096 bf16 = 64 MiB
  unsigned short* Wt = xb + (size_t)M_TOK * K_IN;                // 4096*4096 bf16 = 32 MiB

  cvt_x_kernel<<<(M_TOK * (long)K_IN) / (256 * 8), 256, 0, stream>>>(x, xb);
  dequant_had_kernel<<<N_OUT * 4, 256, 0, stream>>>(codes, grid, scales, Wt);
  gemm_kernel<<<dim3(N_OUT / 128, M_TOK / 128), 256, 0, stream>>>(xb, Wt, bias, out);
}

// Round 2
// 557.525 us; speedup vs baseline: 1.0308x; 1.0308x over previous
//
#include <hip/hip_runtime.h>

#define M_TOK 8192
#define N_OUT 4096
#define K_IN  4096
#define CVT_BLOCKS ((M_TOK * K_IN) / 2048)   // 16384: 256 thr * 8 f32 each
#define DEQ_BLOCKS (N_OUT * 4 / 4)           // 4096: 4 waves/block, 1 group/wave

typedef __bf16 bf16x8 __attribute__((ext_vector_type(8)));
typedef float f32x4 __attribute__((ext_vector_type(4)));

__device__ __forceinline__ unsigned short f2b(float f) {
  union { float f; unsigned u; } c; c.f = f;
  unsigned u = c.u;
  return (unsigned short)((u + 0x7FFFu + ((u >> 16) & 1u)) >> 16);  // RNE
}

// ---------------- kernel 1: fused x-cast + W dequant/FWHT ----------------
__global__ __launch_bounds__(256) void prep_kernel(const float* __restrict__ x,
                                                   unsigned short* __restrict__ xb,
                                                   const int* __restrict__ codes,
                                                   const float* __restrict__ grid,
                                                   const float* __restrict__ scales,
                                                   unsigned short* __restrict__ Wt) {
  if (blockIdx.x < CVT_BLOCKS) {
    // ---- x f32 -> bf16, 8 elems/thread ----
    long i = ((long)blockIdx.x * 256 + threadIdx.x) * 8;
    float4 a = *(const float4*)(x + i);
    float4 b = *(const float4*)(x + i + 4);
    union { unsigned short us[8]; uint4 v; } o;
    o.us[0] = f2b(a.x); o.us[1] = f2b(a.y); o.us[2] = f2b(a.z); o.us[3] = f2b(a.w);
    o.us[4] = f2b(b.x); o.us[5] = f2b(b.y); o.us[6] = f2b(b.z); o.us[7] = f2b(b.w);
    *(uint4*)(xb + i) = o.v;
  } else {
    // ---- dequant + FWHT-1024, one wave per hadamard group ----
    int bid = blockIdx.x - CVT_BLOCKS;
    int wave = threadIdx.x >> 6;
    int lane = threadIdx.x & 63;
    int G = bid * 4 + wave;          // group id 0..16383
    int o = G >> 2;                  // output row
    int g = G & 3;                   // hadamard group within row
    // lane owns elements e = lane*16 + c, c=0..15 -> codes lane*8 + 0..7
    const int* crow = codes + (long)o * 2048 + g * 512 + lane * 8;
    int4 c0 = *(const int4*)crow;
    int4 c1 = *(const int4*)(crow + 4);
    float v[16];
    const float2* g2p = (const float2*)grid;
    float2 t;
    t = g2p[c0.x]; v[0] = t.x;  v[1] = t.y;
    t = g2p[c0.y]; v[2] = t.x;  v[3] = t.y;
    t = g2p[c0.z]; v[4] = t.x;  v[5] = t.y;
    t = g2p[c0.w]; v[6] = t.x;  v[7] = t.y;
    t = g2p[c1.x]; v[8] = t.x;  v[9] = t.y;
    t = g2p[c1.y]; v[10] = t.x; v[11] = t.y;
    t = g2p[c1.z]; v[12] = t.x; v[13] = t.y;
    t = g2p[c1.w]; v[14] = t.x; v[15] = t.y;
    // in-register FWHT stages: strides 1,2,4,8
#pragma unroll
    for (int s = 1; s < 16; s <<= 1) {
#pragma unroll
      for (int base = 0; base < 16; base++) {
        if (!(base & s)) {
          float a = v[base], b = v[base | s];
          v[base] = a + b;
          v[base | s] = a - b;
        }
      }
    }
    // cross-lane FWHT stages: strides 16..512 -> lane masks 1..32
#pragma unroll
    for (int m = 1; m <= 32; m <<= 1) {
      bool hi = (lane & m) != 0;
#pragma unroll
      for (int c = 0; c < 16; c++) {
        float p = __shfl_xor(v[c], m, 64);
        v[c] = hi ? p - v[c] : p + v[c];
      }
    }
    float sc = scales[o * 4 + g] * 0.03125f;  // 1/sqrt(1024)
    union { unsigned short us[16]; uint4 q[2]; } out;
#pragma unroll
    for (int c = 0; c < 16; c++) out.us[c] = f2b(v[c] * sc);
    unsigned short* wp = Wt + (long)o * 4096 + g * 1024 + lane * 16;
    *(uint4*)wp = out.q[0];
    *(uint4*)(wp + 8) = out.q[1];
  }
}

// ---------------- kernel 2: bf16 GEMM, C = A * B^T + bias ----------------
// LDS layout: per 1KB chunk (16 rows x 32 k), granule (row, g) lives at slot
// (g ^ (row&3))*16 + (row&15)  ->  read banks = 4*row mod 32 (conflict-free).
__device__ __forceinline__ void load16_to_lds(const unsigned short* g, unsigned short* l) {
  __builtin_amdgcn_global_load_lds((const __attribute__((address_space(1))) void*)g,
                                   (__attribute__((address_space(3))) void*)l,
                                   16, 0, 0);
}

__global__ __launch_bounds__(256, 2) void gemm_kernel(const unsigned short* __restrict__ A,
                                                      const unsigned short* __restrict__ B,
                                                      const float* __restrict__ bias,
                                                      float* __restrict__ C) {
  __shared__ unsigned short sA[128 * 32];
  __shared__ unsigned short sB[128 * 32];
  const int bm = blockIdx.y * 128;
  const int bn = blockIdx.x * 128;
  const int tid = threadIdx.x;
  const int wave = tid >> 6;
  const int lane = tid & 63;
  const int wm = (wave >> 1) * 64;    // wave's 64x64 subtile
  const int wn = (wave & 1) * 64;

  // staging: lane l fetches global (row = l&15, granule = (l>>4)^(l&3)),
  // lands at LDS slot l (global_load_lds writes base + lane*16)
  const int srow = lane & 15;
  const int scol = ((lane >> 4) ^ (lane & 3)) * 8;   // swizzled k offset (elems)
  const long K = K_IN;
  const unsigned short* Ag0 = A + (long)(bm + wave * 16 + srow) * K + scol;
  const unsigned short* Ag1 = A + (long)(bm + (wave + 4) * 16 + srow) * K + scol;
  const unsigned short* Bg0 = B + (long)(bn + wave * 16 + srow) * K + scol;
  const unsigned short* Bg1 = B + (long)(bn + (wave + 4) * 16 + srow) * K + scol;
  unsigned short* lA0 = &sA[(wave * 16) * 32];       // wave-uniform LDS bases
  unsigned short* lA1 = &sA[((wave + 4) * 16) * 32];
  unsigned short* lB0 = &sB[(wave * 16) * 32];
  unsigned short* lB1 = &sB[((wave + 4) * 16) * 32];

  f32x4 acc[4][4] = {};

  // fragment read: row's chunk = (wm/16 + i); within chunk, slot for
  // (row = lane&15, g = lane>>4) is ((lane>>4)^(lane&3))*16 + (lane&15)
  const int achunk = (wave >> 1) * 4;
  const int bchunk = (wave & 1) * 4;
  const int fslot = ((((lane >> 4) ^ (lane & 3)) * 16) + (lane & 15)) * 8;

  for (int k0 = 0; k0 < K_IN; k0 += 32) {
    __syncthreads();                  // prev iter's LDS reads done
    load16_to_lds(Ag0 + k0, lA0);
    load16_to_lds(Ag1 + k0, lA1);
    load16_to_lds(Bg0 + k0, lB0);
    load16_to_lds(Bg1 + k0, lB1);
    __syncthreads();                  // staging complete
    bf16x8 af[4], bfr[4];
#pragma unroll
    for (int i = 0; i < 4; i++)
      af[i] = *(const bf16x8*)&sA[(achunk + i) * 512 + fslot];
#pragma unroll
    for (int i = 0; i < 4; i++)
      bfr[i] = *(const bf16x8*)&sB[(bchunk + i) * 512 + fslot];
#pragma unroll
    for (int mi = 0; mi < 4; mi++)
#pragma unroll
      for (int ni = 0; ni < 4; ni++)
        acc[mi][ni] = __builtin_amdgcn_mfma_f32_16x16x32_bf16(af[mi], bfr[ni], acc[mi][ni], 0, 0, 0);
  }

  // epilogue: D[m=(lane>>4)*4+r][n=lane&15] per 16x16 tile
  const int cn = lane & 15;
  const int cm = (lane >> 4) * 4;
#pragma unroll
  for (int ni = 0; ni < 4; ni++) {
    const int col = bn + wn + ni * 16 + cn;
    const float bb = bias[col];
#pragma unroll
    for (int mi = 0; mi < 4; mi++) {
#pragma unroll
      for (int r = 0; r < 4; r++) {
        const int row = bm + wm + mi * 16 + cm + r;
        C[(long)row * N_OUT + col] = acc[mi][ni][r] + bb;
      }
    }
  }
}

extern "C" void kernel_launch(void* const* d_in, const int* in_sizes, int n_in,
                              void* d_out, int out_size, void* d_ws, size_t ws_size,
                              hipStream_t stream) {
  const float* x      = (const float*)d_in[0];
  const int*   codes  = (const int*)d_in[1];
  const float* grid   = (const float*)d_in[2];
  const float* scales = (const float*)d_in[3];
  const float* bias   = (const float*)d_in[4];
  float* out = (float*)d_out;

  unsigned short* xb = (unsigned short*)d_ws;                    // 64 MiB bf16
  unsigned short* Wt = xb + (size_t)M_TOK * K_IN;                // 32 MiB bf16

  prep_kernel<<<CVT_BLOCKS + DEQ_BLOCKS, 256, 0, stream>>>(x, xb, codes, grid, scales, Wt);
  gemm_kernel<<<dim3(N_OUT / 128, M_TOK / 128), 256, 0, stream>>>(xb, Wt, bias, out);
}

// Round 4
// 531.521 us; speedup vs baseline: 1.0812x; 1.0489x over previous
//
#include <hip/hip_runtime.h>

#define M_TOK 8192
#define N_OUT 4096
#define K_IN  4096
#define CVT_BLOCKS ((M_TOK * K_IN) / 2048)   // 16384: 256 thr * 8 f32 each
#define DEQ_BLOCKS (N_OUT * 4 / 4)           // 4096: 4 waves/block, 1 group/wave

typedef __bf16 bf16x8 __attribute__((ext_vector_type(8)));
typedef float f32x4 __attribute__((ext_vector_type(4)));

__device__ __forceinline__ unsigned short f2b(float f) {
  union { float f; unsigned u; } c; c.f = f;
  unsigned u = c.u;
  return (unsigned short)((u + 0x7FFFu + ((u >> 16) & 1u)) >> 16);  // RNE
}

// ---------------- kernel 1: fused x-cast + W dequant/FWHT ----------------
__global__ __launch_bounds__(256) void prep_kernel(const float* __restrict__ x,
                                                   unsigned short* __restrict__ xb,
                                                   const int* __restrict__ codes,
                                                   const float* __restrict__ grid,
                                                   const float* __restrict__ scales,
                                                   unsigned short* __restrict__ Wt) {
  if (blockIdx.x < CVT_BLOCKS) {
    // ---- x f32 -> bf16, 8 elems/thread ----
    long i = ((long)blockIdx.x * 256 + threadIdx.x) * 8;
    float4 a = *(const float4*)(x + i);
    float4 b = *(const float4*)(x + i + 4);
    union { unsigned short us[8]; uint4 v; } o;
    o.us[0] = f2b(a.x); o.us[1] = f2b(a.y); o.us[2] = f2b(a.z); o.us[3] = f2b(a.w);
    o.us[4] = f2b(b.x); o.us[5] = f2b(b.y); o.us[6] = f2b(b.z); o.us[7] = f2b(b.w);
    *(uint4*)(xb + i) = o.v;
  } else {
    // ---- dequant + FWHT-1024, one wave per hadamard group ----
    int bid = blockIdx.x - CVT_BLOCKS;
    int wave = threadIdx.x >> 6;
    int lane = threadIdx.x & 63;
    int G = bid * 4 + wave;          // group id 0..16383
    int o = G >> 2;                  // output row
    int g = G & 3;                   // hadamard group within row
    // lane owns elements e = lane*16 + c, c=0..15 -> codes lane*8 + 0..7
    const int* crow = codes + (long)o * 2048 + g * 512 + lane * 8;
    int4 c0 = *(const int4*)crow;
    int4 c1 = *(const int4*)(crow + 4);
    float v[16];
    const float2* g2p = (const float2*)grid;
    float2 t;
    t = g2p[c0.x]; v[0] = t.x;  v[1] = t.y;
    t = g2p[c0.y]; v[2] = t.x;  v[3] = t.y;
    t = g2p[c0.z]; v[4] = t.x;  v[5] = t.y;
    t = g2p[c0.w]; v[6] = t.x;  v[7] = t.y;
    t = g2p[c1.x]; v[8] = t.x;  v[9] = t.y;
    t = g2p[c1.y]; v[10] = t.x; v[11] = t.y;
    t = g2p[c1.z]; v[12] = t.x; v[13] = t.y;
    t = g2p[c1.w]; v[14] = t.x; v[15] = t.y;
    // in-register FWHT stages: strides 1,2,4,8
#pragma unroll
    for (int s = 1; s < 16; s <<= 1) {
#pragma unroll
      for (int base = 0; base < 16; base++) {
        if (!(base & s)) {
          float a = v[base], b = v[base | s];
          v[base] = a + b;
          v[base | s] = a - b;
        }
      }
    }
    // cross-lane FWHT stages: strides 16..512 -> lane masks 1..32
#pragma unroll
    for (int m = 1; m <= 32; m <<= 1) {
      bool hi = (lane & m) != 0;
#pragma unroll
      for (int c = 0; c < 16; c++) {
        float p = __shfl_xor(v[c], m, 64);
        v[c] = hi ? p - v[c] : p + v[c];
      }
    }
    float sc = scales[o * 4 + g] * 0.03125f;  // 1/sqrt(1024)
    union { unsigned short us[16]; uint4 q[2]; } out;
#pragma unroll
    for (int c = 0; c < 16; c++) out.us[c] = f2b(v[c] * sc);
    unsigned short* wp = Wt + (long)o * 4096 + g * 1024 + lane * 16;
    *(uint4*)wp = out.q[0];
    *(uint4*)(wp + 8) = out.q[1];
  }
}

// ---------------- kernel 2: bf16 GEMM, C = A * B^T + bias, BK = 64 ----------------
// LDS chunk = 16 rows x 64 k-elems = 1024 elements (2 KB), as 128 granule-slots
// of 8 elems. Half h (k = h*32..h*32+31): slot(row,g2) = h*512 + (g2^(row&3))*128/8...
// staged: issue h of a chunk -> lane l fetches (row=l&15, g2=(l>>4)^(l&3)) at
// k-offset h*32 + g2*8, lands at chunk_base + h*512 + l*8 elems.
// Fragment read within half: slot8 = ((gneed^(row&3))*16 + row)*8, gneed=lane>>4.
__device__ __forceinline__ void load16_to_lds(const unsigned short* g, unsigned short* l) {
  __builtin_amdgcn_global_load_lds((const __attribute__((address_space(1))) void*)g,
                                   (__attribute__((address_space(3))) void*)l,
                                   16, 0, 0);
}

__global__ __launch_bounds__(256, 2) void gemm_kernel(const unsigned short* __restrict__ A,
                                                      const unsigned short* __restrict__ B,
                                                      const float* __restrict__ bias,
                                                      float* __restrict__ C) {
  __shared__ unsigned short sA[128 * 64];   // 8 chunks x 1024 elems
  __shared__ unsigned short sB[128 * 64];
  const int bm = blockIdx.y * 128;
  const int bn = blockIdx.x * 128;
  const int tid = threadIdx.x;
  const int wave = tid >> 6;
  const int lane = tid & 63;

  const int srow = lane & 15;
  const int scol = ((lane >> 4) ^ (lane & 3)) * 8;   // elems within 32-k half
  const long K = K_IN;
  const unsigned short* Ag0 = A + (long)(bm + wave * 16 + srow) * K + scol;
  const unsigned short* Ag1 = A + (long)(bm + (wave + 4) * 16 + srow) * K + scol;
  const unsigned short* Bg0 = B + (long)(bn + wave * 16 + srow) * K + scol;
  const unsigned short* Bg1 = B + (long)(bn + (wave + 4) * 16 + srow) * K + scol;
  unsigned short* lA0 = &sA[wave * 1024];            // wave-uniform LDS bases
  unsigned short* lA1 = &sA[(wave + 4) * 1024];
  unsigned short* lB0 = &sB[wave * 1024];
  unsigned short* lB1 = &sB[(wave + 4) * 1024];

  f32x4 acc[4][4] = {};

  const int achunk = (wave >> 1) * 4;   // wave's 64x64 subtile: rows achunk*16..
  const int bchunk = (wave & 1) * 4;
  const int fslot8 = ((((lane >> 4) ^ (lane & 3)) * 16) + (lane & 15)) * 8;

  for (int k0 = 0; k0 < K_IN; k0 += 64) {
    __syncthreads();                  // prev iter's LDS reads done
    load16_to_lds(Ag0 + k0,      lA0);
    load16_to_lds(Ag0 + k0 + 32, lA0 + 512);
    load16_to_lds(Ag1 + k0,      lA1);
    load16_to_lds(Ag1 + k0 + 32, lA1 + 512);
    load16_to_lds(Bg0 + k0,      lB0);
    load16_to_lds(Bg0 + k0 + 32, lB0 + 512);
    load16_to_lds(Bg1 + k0,      lB1);
    load16_to_lds(Bg1 + k0 + 32, lB1 + 512);
    __syncthreads();                  // staging complete
#pragma unroll
    for (int kstep = 0; kstep < 2; kstep++) {
      bf16x8 af[4], bfr[4];
#pragma unroll
      for (int i = 0; i < 4; i++)
        af[i] = *(const bf16x8*)&sA[(achunk + i) * 1024 + kstep * 512 + fslot8];
#pragma unroll
      for (int i = 0; i < 4; i++)
        bfr[i] = *(const bf16x8*)&sB[(bchunk + i) * 1024 + kstep * 512 + fslot8];
#pragma unroll
      for (int mi = 0; mi < 4; mi++)
#pragma unroll
        for (int ni = 0; ni < 4; ni++)
          acc[mi][ni] = __builtin_amdgcn_mfma_f32_16x16x32_bf16(af[mi], bfr[ni], acc[mi][ni], 0, 0, 0);
    }
  }

  // epilogue: D[m=(lane>>4)*4+r][n=lane&15] per 16x16 tile
  const int wm = (wave >> 1) * 64;
  const int wn = (wave & 1) * 64;
  const int cn = lane & 15;
  const int cm = (lane >> 4) * 4;
#pragma unroll
  for (int ni = 0; ni < 4; ni++) {
    const int col = bn + wn + ni * 16 + cn;
    const float bb = bias[col];
#pragma unroll
    for (int mi = 0; mi < 4; mi++) {
#pragma unroll
      for (int r = 0; r < 4; r++) {
        const int row = bm + wm + mi * 16 + cm + r;
        C[(long)row * N_OUT + col] = acc[mi][ni][r] + bb;
      }
    }
  }
}

extern "C" void kernel_launch(void* const* d_in, const int* in_sizes, int n_in,
                              void* d_out, int out_size, void* d_ws, size_t ws_size,
                              hipStream_t stream) {
  const float* x      = (const float*)d_in[0];
  const int*   codes  = (const int*)d_in[1];
  const float* grid   = (const float*)d_in[2];
  const float* scales = (const float*)d_in[3];
  const float* bias   = (const float*)d_in[4];
  float* out = (float*)d_out;

  unsigned short* xb = (unsigned short*)d_ws;                    // 64 MiB bf16
  unsigned short* Wt = xb + (size_t)M_TOK * K_IN;                // 32 MiB bf16

  prep_kernel<<<CVT_BLOCKS + DEQ_BLOCKS, 256, 0, stream>>>(x, xb, codes, grid, scales, Wt);
  gemm_kernel<<<dim3(N_OUT / 128, M_TOK / 128), 256, 0, stream>>>(xb, Wt, bias, out);
}